// Round 10
// baseline (198.969 us; speedup 1.0000x reference)
//
#include <hip/hip_runtime.h>
#include <hip/hip_cooperative_groups.h>

namespace cg = cooperative_groups;

typedef __bf16 bf16x8 __attribute__((ext_vector_type(8)));
typedef float f32x16 __attribute__((ext_vector_type(16)));
typedef unsigned int uint4v __attribute__((ext_vector_type(4)));
typedef unsigned int uint2v __attribute__((ext_vector_type(2)));
typedef unsigned short u16;

#define MFMA32(a, b, c) __builtin_amdgcn_mfma_f32_32x32x16_bf16((a), (b), (c), 0, 0, 0)

static __device__ __forceinline__ u16 f2bf(float f) {
  unsigned u = __builtin_bit_cast(unsigned, f);
  u += 0x7fffu + ((u >> 16) & 1u);
  return (u16)(u >> 16);
}

static __device__ __forceinline__ f32x16 zero16() {
  f32x16 z;
#pragma unroll
  for (int i = 0; i < 16; ++i) z[i] = 0.0f;
  return z;
}

// Fragment-major 32x32 bf16 operand tile: frag_s[lane][i] =
// T[lane&31][s*16 + 8*(lane>>5) + i], stored buf[(tile*16+s)*512 + lane*8+i].
//
// Single cooperative kernel, 256 blocks x 512 threads (1 block/CU):
//  P0: waves 0-1 convert 2 weight (ot,s) units each -> wqf/wpf.   grid.sync
//  P1: LN (block = 32-token m-tile) -> A frags in LDS -> 8 waves x
//      3 o-tiles QKV GEMM -> qg/kf/vf (fragment-major).           grid.sync
//  P2: attn (wave w = head w, 128 KV tiles, no-max softmax +
//      magic-exp2) + proj GEMM + bias + residual + token2patch.
__global__ __launch_bounds__(512) void fused_kernel(
    const float* __restrict__ x, const float* __restrict__ gamma,
    const float* __restrict__ beta, const float* __restrict__ wq,
    const float* __restrict__ wp, const float* __restrict__ bpj,
    u16* __restrict__ wqf, u16* __restrict__ wpf,
    u16* __restrict__ qg, u16* __restrict__ kf, u16* __restrict__ vf,
    float* __restrict__ out) {
  __shared__ __align__(16) char smem[55680];
  // phase-1 layout
  float (*xs)[257] = reinterpret_cast<float (*)[257]>(smem);          // 32896 B
  u16* af          = reinterpret_cast<u16*>(smem + 32896);            // 16384 B
  float (*red)[16][32] = reinterpret_cast<float (*)[16][32]>(smem + 49280); // 4096 B
  float* mu_s = reinterpret_cast<float*>(smem + 53376);
  float* rs_s = reinterpret_cast<float*>(smem + 53504);
  float* gs   = reinterpret_cast<float*>(smem + 53632);
  float* bs   = reinterpret_cast<float*>(smem + 54656);
  // aliased after xs is dead (post af-barrier):
  u16 (*lsb)[32][32] = reinterpret_cast<u16 (*)[32][32]>(smem);       // 16384 B
  // phase-2 layout (after grid sync; everything above dead):
  u16 (*ls_all)[32][32] = reinterpret_cast<u16 (*)[32][32]>(smem);    // 16384 B
  float (*lsf)[32][33] = reinterpret_cast<float (*)[32][33]>(smem + 16384);

  cg::grid_group grid = cg::this_grid();
  int t = threadIdx.x;
  int bid = blockIdx.x;
  int l = t & 63, w = t >> 6, lo = l & 31, hi = l >> 5;

  // ---------------- P0: weight conversion (waves 0-1) ----------------
  if (w < 2) {
    int u = (bid << 1) + w;            // 0..511
    const float* src; u16* dst; int ot, s;
    if (u < 384) { ot = u >> 4; s = u & 15; src = wq; dst = wqf; }
    else { int u2 = u - 384; ot = u2 >> 4; s = u2 & 15; src = wp; dst = wpf; }
    const float* p = src + (ot * 32 + lo) * 256 + s * 16 + 8 * hi;
    bf16x8 f;
#pragma unroll
    for (int i = 0; i < 8; ++i) f[i] = (__bf16)p[i];
    *(bf16x8*)(dst + (ot * 16 + s) * 512 + l * 8) = f;
  }
  grid.sync();

  // ---------------- P1: LayerNorm + QKV GEMM ----------------
  {
    int mt = bid;
    int n0g = mt * 32;
    int bb = n0g >> 12, nn = n0g & 4095;
    int ni = t & 31, g = t >> 5;       // g in 0..15
    if (t < 256) { gs[t] = gamma[t]; bs[t] = beta[t]; }
    float s1 = 0.f, s2 = 0.f;
    for (int c = g; c < 256; c += 16) {
      float v = x[(((bb << 8) + c) << 12) + nn + ni];
      xs[ni][c] = v;
      s1 += v; s2 += v * v;
    }
    red[0][g][ni] = s1; red[1][g][ni] = s2;
    __syncthreads();
    if (t < 32) {
      float ss = 0.f, qq = 0.f;
#pragma unroll
      for (int k = 0; k < 16; ++k) { ss += red[0][k][t]; qq += red[1][k][t]; }
      float mean = ss * (1.f / 256.f);
      float var = qq * (1.f / 256.f) - mean * mean;
      mu_s[t] = mean;
      rs_s[t] = rsqrtf(var + 1e-5f);
    }
    __syncthreads();
    {
      float mu = mu_s[lo], rs = rs_s[lo];
#pragma unroll
      for (int jj = 0; jj < 2; ++jj) {
        int s = w * 2 + jj;
        bf16x8 f;
#pragma unroll
        for (int i = 0; i < 8; ++i) {
          int c = s * 16 + 8 * hi + i;
          f[i] = (__bf16)((xs[lo][c] - mu) * rs * gs[c] + bs[c]);
        }
        *(bf16x8*)(af + s * 512 + l * 8) = f;
      }
    }
    __syncthreads();   // af complete; xs dead -> lsb may alias it

    bf16x8 ar[16];
#pragma unroll
    for (int s = 0; s < 16; ++s) ar[s] = *(const bf16x8*)(af + s * 512 + l * 8);
    const float sl2e = 0.17677669529663688f * 1.4426950408889634f;
    int n0 = n0g & 4095;
    int tt = n0 >> 5;
#pragma unroll
    for (int oi = 0; oi < 3; ++oi) {
      int ot = w * 3 + oi;
      int o0 = ot * 32;
      f32x16 acc = zero16();
      const bf16x8* bp = (const bf16x8*)(wqf + (ot * 16) * 512 + l * 8);
#pragma unroll
      for (int s = 0; s < 16; ++s) acc = MFMA32(ar[s], bp[s * 64], acc);
      int sec = o0 >> 8;              // 0=q 1=k 2=v
      int hh = (o0 & 255) >> 5;       // head
      float mul = (sec == 0) ? sl2e : 1.0f;
      if (sec == 2) {
#pragma unroll
        for (int r = 0; r < 16; ++r) {
          int row = (r & 3) + 8 * (r >> 2) + 4 * hi;
          lsb[w][lo][row] = f2bf(acc[r]);          // transposed: [d][token]
        }
      } else {
#pragma unroll
        for (int r = 0; r < 16; ++r) {
          int row = (r & 3) + 8 * (r >> 2) + 4 * hi;
          lsb[w][row][lo] = f2bf(acc[r] * mul);    // [token][d]
        }
      }
      // same-wave LDS write->read: ordered by data dependency (lgkmcnt)
      int bh = (bb << 3) + hh;
      if (sec == 0) {
        u16* dst = qg + (((bh << 12) + n0 + (l >> 1)) << 5) + (l & 1) * 16;
        const u16* srow = &lsb[w][l >> 1][(l & 1) * 16];
        *(uint4v*)(dst) = *(const uint4v*)(srow);
        *(uint4v*)(dst + 8) = *(const uint4v*)(srow + 8);
      } else {
        u16* base = (sec == 1) ? kf : vf;
        u16* dst = base + ((bh * 128 + tt) * 2) * 512 + l * 8;
        *(uint4v*)(dst) = *(const uint4v*)&lsb[w][lo][8 * hi];
        *(uint4v*)(dst + 512) = *(const uint4v*)&lsb[w][lo][16 + 8 * hi];
      }
    }
  }
  grid.sync();

  // ---------------- P2: attention + proj + residual ----------------
  {
    int b = bid >> 7, qt = bid & 127;
    int bh = (b << 3) + w;              // wave w owns head w
    const u16* qp = qg + (((bh << 12) + qt * 32 + lo) << 5);
    bf16x8 qf0 = *(const bf16x8*)(qp + hi * 8);
    bf16x8 qf1 = *(const bf16x8*)(qp + 16 + hi * 8);
    const u16* kfb = kf + (size_t)bh * 131072 + l * 8;
    const u16* vfb = vf + (size_t)bh * 131072 + l * 8;
    const f32x16 zf = zero16();
    f32x16 oacc = zero16();
    f32x16 lacc = zero16();
    const uint4v onesu = {0x3F803F80u, 0x3F803F80u, 0x3F803F80u, 0x3F803F80u};
    const bf16x8 ones8 = __builtin_bit_cast(bf16x8, onesu);

#define LOADT(T, K0, K1, V0, V1) do {                  \
    const u16* kq_ = kfb + (T) * 1024;                 \
    const u16* vq_ = vfb + (T) * 1024;                 \
    K0 = *(const bf16x8*)(kq_);                        \
    K1 = *(const bf16x8*)(kq_ + 512);                  \
    V0 = *(const bf16x8*)(vq_);                        \
    V1 = *(const bf16x8*)(vq_ + 512);                  \
  } while (0)

// exp2 in bf16 bit-domain via float-add magic (x*128 exact); one v_perm
// packs a bf16 pair. No max tracking: |s| bounded ~2 by construction.
#define ABODY(K0, K1, V0, V1) do {                                          \
    f32x16 sa = MFMA32(K0, qf0, zf);                                        \
    sa = MFMA32(K1, qf1, sa);                                               \
    f32x16 tmag = sa * 128.0f + 8404864.0f;                                 \
    unsigned pk[8];                                                         \
    _Pragma("unroll")                                                       \
    for (int j = 0; j < 8; ++j) {                                           \
      pk[j] = __builtin_amdgcn_perm(                                        \
          __builtin_bit_cast(unsigned, tmag[2 * j + 1]),                    \
          __builtin_bit_cast(unsigned, tmag[2 * j]), 0x05040100u);          \
    }                                                                       \
    uint2v A0 = __builtin_amdgcn_permlane32_swap(pk[0], pk[2], false, false); \
    uint2v A1 = __builtin_amdgcn_permlane32_swap(pk[1], pk[3], false, false); \
    uint2v B0 = __builtin_amdgcn_permlane32_swap(pk[4], pk[6], false, false); \
    uint2v B1 = __builtin_amdgcn_permlane32_swap(pk[5], pk[7], false, false); \
    uint4v u0v = {A0[0], A1[0], A0[1], A1[1]};                              \
    uint4v u1v = {B0[0], B1[0], B0[1], B1[1]};                              \
    bf16x8 p0 = __builtin_bit_cast(bf16x8, u0v);                            \
    bf16x8 p1 = __builtin_bit_cast(bf16x8, u1v);                            \
    __builtin_amdgcn_s_setprio(1);                                          \
    oacc = MFMA32(V0, p0, oacc);                                            \
    lacc = MFMA32(ones8, p0, lacc);                                         \
    oacc = MFMA32(V1, p1, oacc);                                            \
    lacc = MFMA32(ones8, p1, lacc);                                         \
    __builtin_amdgcn_s_setprio(0);                                          \
  } while (0)

    bf16x8 ak0, ak1, av0, av1, bk0, bk1, bv0, bv1;
    LOADT(0, ak0, ak1, av0, av1);
    LOADT(1, bk0, bk1, bv0, bv1);
    for (int tt = 0; tt < 128; tt += 2) {
      bf16x8 ck0, ck1, cv0, cv1, dk0, dk1, dv0, dv1;
      if (tt + 2 < 128) LOADT(tt + 2, ck0, ck1, cv0, cv1);
      ABODY(ak0, ak1, av0, av1);
      if (tt + 3 < 128) LOADT(tt + 3, dk0, dk1, dv0, dv1);
      ABODY(bk0, bk1, bv0, bv1);
      ak0 = ck0; ak1 = ck1; av0 = cv0; av1 = cv1;
      bk0 = dk0; bk1 = dk1; bv0 = dv0; bv1 = dv1;
    }
#undef LOADT
#undef ABODY

    // normalize and publish O for this head: ls_all[w][q][d]
    float inv = 1.0f / lacc[0];
#pragma unroll
    for (int r = 0; r < 16; ++r) {
      int row = (r & 3) + 8 * (r >> 2) + 4 * hi;
      ls_all[w][lo][row] = f2bf(oacc[r] * inv);
    }
    __syncthreads();

    // ---- proj GEMM: wave w computes out cols [w*32, w*32+32) ----
    f32x16 acc = zero16();
    const bf16x8* bp = (const bf16x8*)(wpf + (w * 16) * 512 + l * 8);
#pragma unroll
    for (int s = 0; s < 16; ++s) {
      bf16x8 afr = *(const bf16x8*)&ls_all[s >> 1][lo][(s & 1) * 16 + 8 * hi];
      acc = MFMA32(afr, bp[s * 64], acc);
    }
    int c0 = w * 32;
    float bias = bpj[c0 + lo];
#pragma unroll
    for (int r = 0; r < 16; ++r) {
      int row = (r & 3) + 8 * (r >> 2) + 4 * hi;
      lsf[w][row][lo] = acc[r] + bias;        // [token][col], per-wave
    }
    // lsf written and read by the same wave: no barrier needed.
    int n0 = qt * 32;
#pragma unroll
    for (int r2 = 0; r2 < 16; ++r2) {
      int cl = 2 * r2 + hi;
      int idx = (((b << 8) + c0 + cl) << 12) + n0 + lo;
      out[idx] = lsf[w][lo][cl] + x[idx];
    }
  }
}

extern "C" void kernel_launch(void* const* d_in, const int* in_sizes, int n_in,
                              void* d_out, int out_size, void* d_ws, size_t ws_size,
                              hipStream_t stream) {
  const float* x      = (const float*)d_in[0];
  const float* gamma  = (const float*)d_in[1];
  const float* beta   = (const float*)d_in[2];
  const float* w_qkv  = (const float*)d_in[3];
  const float* w_proj = (const float*)d_in[4];
  const float* b_proj = (const float*)d_in[5];
  float* out = (float*)d_out;
  char* ws = (char*)d_ws;
  const size_t MB = 1024 * 1024;
  u16* qg  = (u16*)(ws);            // 4 MB [16][4096][32]
  u16* kf  = (u16*)(ws + 4 * MB);   // 4 MB K fragments [16][128][2][512]
  u16* vf  = (u16*)(ws + 8 * MB);   // 4 MB V fragments
  u16* wqf = (u16*)(ws + 12 * MB);  // 384 KB
  u16* wpf = (u16*)(ws + 12 * MB + 768 * 256 * sizeof(u16)); // 128 KB

  void* args[] = {
    (void*)&x, (void*)&gamma, (void*)&beta, (void*)&w_qkv, (void*)&w_proj,
    (void*)&b_proj, (void*)&wqf, (void*)&wpf, (void*)&qg, (void*)&kf,
    (void*)&vf, (void*)&out
  };
  hipLaunchCooperativeKernel((const void*)fused_kernel, dim3(256), dim3(512),
                             args, 0, stream);
}

// Round 12
// 128.036 us; speedup vs baseline: 1.5540x; 1.5540x over previous
//
#include <hip/hip_runtime.h>

typedef __bf16 bf16x8 __attribute__((ext_vector_type(8)));
typedef float f32x16 __attribute__((ext_vector_type(16)));
typedef unsigned int uint4v __attribute__((ext_vector_type(4)));
typedef unsigned int uint2v __attribute__((ext_vector_type(2)));
typedef long long2v __attribute__((ext_vector_type(2)));
typedef unsigned short u16;
typedef unsigned char u8;

#define MFMA32(a, b, c) __builtin_amdgcn_mfma_f32_32x32x16_bf16((a), (b), (c), 0, 0, 0)
#define MFMA8(a, b, c) __builtin_amdgcn_mfma_f32_32x32x16_fp8_fp8((a), (b), (c), 0, 0, 0)

static __device__ __forceinline__ u16 f2bf(float f) {
  unsigned u = __builtin_bit_cast(unsigned, f);
  u += 0x7fffu + ((u >> 16) & 1u);
  return (u16)(u >> 16);
}

static __device__ __forceinline__ f32x16 zero16() {
  f32x16 z;
#pragma unroll
  for (int i = 0; i < 16; ++i) z[i] = 0.0f;
  return z;
}

// bf16 fragment-major (for GEMM operands): frag_s[lane][i] =
//   T[lane&31][s*16 + 8*(lane>>5) + i], buf[(tile*16+s)*512 + lane*8 + i].
// fp8 fragment-major (for attn operands), 1 KB per 32x32 tile:
//   lane l holds 16 bytes: j=0..7  -> T[l&31][(l>>5)*8 + j]
//                          j=8..15 -> T[l&31][16 + (l>>5)*8 + j]
//   (T = K: [kvrow][d]; T = Q: [qrow][d]; T = V^T: [d][kvrow])

// ---------------- weights fp32 -> bf16 fragment-major ----------------
__global__ __launch_bounds__(256) void convw_kernel(
    const float* __restrict__ wq, const float* __restrict__ wp,
    u16* __restrict__ wqf, u16* __restrict__ wpf) {
  int t = threadIdx.x;
  int u = (blockIdx.x << 2) + (t >> 6);
  int l = t & 63, lo = l & 31, hi = l >> 5;
  const float* src; u16* dst; int ot, s;
  if (u < 384) { ot = u >> 4; s = u & 15; src = wq; dst = wqf; }
  else { int u2 = u - 384; ot = u2 >> 4; s = u2 & 15; src = wp; dst = wpf; }
  const float* p = src + (ot * 32 + lo) * 256 + s * 16 + 8 * hi;
  bf16x8 f;
#pragma unroll
  for (int i = 0; i < 8; ++i) f[i] = (__bf16)p[i];
  *(bf16x8*)(dst + (ot * 16 + s) * 512 + l * 8) = f;
}

// ---------- fused LayerNorm + QKV GEMM, fp8 fragment outputs ----------
__global__ __launch_bounds__(256) void prepqkv_kernel(
    const float* __restrict__ x, const float* __restrict__ gamma,
    const float* __restrict__ beta, const u16* __restrict__ wqf,
    u8* __restrict__ qgf, u8* __restrict__ kgf, u8* __restrict__ vgf) {
  __shared__ float xs[32][257];
  __shared__ float red[2][8][32];
  __shared__ float mu_s[32], rs_s[32];
  __shared__ float gs[256], bs[256];
  __shared__ u16 af[16 * 512];        // A fragments (bf16), 16 KB
  __shared__ u8 ls8[4][32][32];       // per-wave fp8 transpose bounce, 4 KB
  int t = threadIdx.x;
  int mt = blockIdx.x;
  int n0g = mt * 32;
  int bb = n0g >> 12, nn = n0g & 4095;
  int ni = t & 31, g = t >> 5;
  gs[t] = gamma[t]; bs[t] = beta[t];
  float s1 = 0.f, s2 = 0.f;
  for (int c = g; c < 256; c += 8) {
    float v = x[(((bb << 8) + c) << 12) + nn + ni];
    xs[ni][c] = v;
    s1 += v; s2 += v * v;
  }
  red[0][g][ni] = s1; red[1][g][ni] = s2;
  __syncthreads();
  if (t < 32) {
    float ss = 0.f, qq = 0.f;
#pragma unroll
    for (int k = 0; k < 8; ++k) { ss += red[0][k][t]; qq += red[1][k][t]; }
    float mean = ss * (1.f / 256.f);
    float var = qq * (1.f / 256.f) - mean * mean;
    mu_s[t] = mean;
    rs_s[t] = rsqrtf(var + 1e-5f);
  }
  __syncthreads();
  int l = t & 63, w = t >> 6, lo = l & 31, hi = l >> 5;
  {
    float mu = mu_s[lo], rs = rs_s[lo];
#pragma unroll
    for (int jj = 0; jj < 4; ++jj) {
      int s = w * 4 + jj;
      bf16x8 f;
#pragma unroll
      for (int i = 0; i < 8; ++i) {
        int c = s * 16 + 8 * hi + i;
        f[i] = (__bf16)((xs[lo][c] - mu) * rs * gs[c] + bs[c]);
      }
      *(bf16x8*)(af + s * 512 + l * 8) = f;
    }
  }
  __syncthreads();

  // ---- phase 2: A-tile in registers, 6 o-tiles per wave, fp8 epilogue ----
  bf16x8 ar[16];
#pragma unroll
  for (int s = 0; s < 16; ++s) ar[s] = *(const bf16x8*)(af + s * 512 + l * 8);
  int n0 = n0g & 4095;
  int tt = n0 >> 5;                 // token tile within batch
#pragma unroll
  for (int oi = 0; oi < 6; ++oi) {
    int ot = w * 6 + oi;
    int o0 = ot * 32;
    f32x16 acc = zero16();
    const bf16x8* bp = (const bf16x8*)(wqf + (ot * 16) * 512 + l * 8);
#pragma unroll
    for (int s = 0; s < 16; ++s) acc = MFMA32(ar[s], bp[s * 64], acc);
    int sec = o0 >> 8;              // 0=q 1=k 2=v
    int hh = (o0 & 255) >> 5;       // head; d = lo
    // convert to fp8 e4m3 and transpose-bounce through LDS.
    // acc[r]: token = (r&3)+8*(r>>2)+4*hi (pairs r,r+1 are adjacent tokens)
    if (sec == 2) {
      // V^T layout: ls8[d][token]; adjacent tokens -> u16 store
#pragma unroll
      for (int j = 0; j < 8; ++j) {
        int rr = 2 * j;
        int row = (rr & 3) + 8 * (rr >> 2) + 4 * hi;
        int pk2 = __builtin_amdgcn_cvt_pk_fp8_f32(acc[rr], acc[rr + 1], 0, false);
        *(u16*)&ls8[w][lo][row] = (u16)pk2;
      }
    } else {
      // Q/K layout: ls8[token][d]
#pragma unroll
      for (int j = 0; j < 8; ++j) {
        int rr = 2 * j;
        int row = (rr & 3) + 8 * (rr >> 2) + 4 * hi;
        int pk2 = __builtin_amdgcn_cvt_pk_fp8_f32(acc[rr], acc[rr + 1], 0, false);
        ls8[w][row][lo] = (u8)pk2;
        ls8[w][row + 1][lo] = (u8)(pk2 >> 8);
      }
    }
    // fragment read: row lo, bytes [hi*8,+8) and [16+hi*8,+8)
    unsigned long long w0 = *(const unsigned long long*)&ls8[w][lo][hi * 8];
    unsigned long long w1 = *(const unsigned long long*)&ls8[w][lo][16 + hi * 8];
    int bh = (bb << 3) + hh;
    u8* base = (sec == 0) ? qgf : ((sec == 1) ? kgf : vgf);
    u8* dst = base + (((size_t)bh * 128 + tt) << 10) + l * 16;
    ((unsigned long long*)dst)[0] = w0;
    ((unsigned long long*)dst)[1] = w1;
  }
}

// ---------- Fused attention (fp8) + proj + residual + token2patch ----------
// Block = (b, qt), 8 waves, wave w = head w, 128 KV tiles.
// QK^T and PV via mfma_f32_32x32x16_fp8_fp8 (half the L2 bytes of bf16).
// No-max softmax; P -> fp8 e4m3 via Schraudolph in the e4m3 bit-domain:
// bits = round(8*s' + 56) where s' = raw_score * scale * log2e, computed as
// one FMA: t = fma(sa, 8*sl2e, 2^23 + 56); byte0 of bits(t) is the fp8 of P.
__global__ __launch_bounds__(512) void attn_proj_kernel(
    const u8* __restrict__ qgf, const u8* __restrict__ kgf,
    const u8* __restrict__ vgf, const u16* __restrict__ wpf,
    const float* __restrict__ bpj, const float* __restrict__ x,
    float* __restrict__ out) {
  __shared__ u16 ls_all[8][32][32];   // O[head][q][d] bf16, normalized
  __shared__ float lsf[8][32][33];    // proj epilogue bounce, per wave
  int t = threadIdx.x;
  int l = t & 63, w = t >> 6, lo = l & 31, hi = l >> 5;
  int b = blockIdx.x >> 7, qt = blockIdx.x & 127;
  int bh = (b << 3) + w;              // wave w owns head w
  long2v qf = *(const long2v*)(qgf + (((size_t)bh * 128 + qt) << 10) + l * 16);
  const u8* kfb = kgf + (size_t)bh * 131072 + l * 16;
  const u8* vfb = vgf + (size_t)bh * 131072 + l * 16;
  const f32x16 zf = zero16();
  f32x16 oacc = zero16();
  f32x16 lacc = zero16();
  const long ONES8 = 0x3838383838383838L;  // e4m3 1.0 x8
  const float C1 = 8.0f * 0.17677669529663688f * 1.4426950408889634f;
  const float C2 = 8388664.0f;             // 2^23 + 56 (e4m3 exp bias<<3)

#define LOADT(T, KK, VV) do {                          \
    KK = *(const long2v*)(kfb + (T) * 1024);           \
    VV = *(const long2v*)(vfb + (T) * 1024);           \
  } while (0)

#define ABODY(KK, VV) do {                                                  \
    f32x16 sa = MFMA8(KK[0], qf[0], zf);                                    \
    sa = MFMA8(KK[1], qf[1], sa);                                           \
    f32x16 tm = sa * C1 + C2;                                               \
    unsigned QA, QB, QC, QD;                                                \
    {                                                                       \
      unsigned ya, yb;                                                      \
      ya = __builtin_amdgcn_perm(__builtin_bit_cast(unsigned, tm[1]),       \
                                 __builtin_bit_cast(unsigned, tm[0]),       \
                                 0x00000400u);                              \
      yb = __builtin_amdgcn_perm(__builtin_bit_cast(unsigned, tm[3]),       \
                                 __builtin_bit_cast(unsigned, tm[2]),       \
                                 0x00000400u);                              \
      QA = __builtin_amdgcn_perm(yb, ya, 0x05040100u);                      \
      ya = __builtin_amdgcn_perm(__builtin_bit_cast(unsigned, tm[5]),       \
                                 __builtin_bit_cast(unsigned, tm[4]),       \
                                 0x00000400u);                              \
      yb = __builtin_amdgcn_perm(__builtin_bit_cast(unsigned, tm[7]),       \
                                 __builtin_bit_cast(unsigned, tm[6]),       \
                                 0x00000400u);                              \
      QB = __builtin_amdgcn_perm(yb, ya, 0x05040100u);                      \
      ya = __builtin_amdgcn_perm(__builtin_bit_cast(unsigned, tm[9]),       \
                                 __builtin_bit_cast(unsigned, tm[8]),       \
                                 0x00000400u);                              \
      yb = __builtin_amdgcn_perm(__builtin_bit_cast(unsigned, tm[11]),      \
                                 __builtin_bit_cast(unsigned, tm[10]),      \
                                 0x00000400u);                              \
      QC = __builtin_amdgcn_perm(yb, ya, 0x05040100u);                      \
      ya = __builtin_amdgcn_perm(__builtin_bit_cast(unsigned, tm[13]),      \
                                 __builtin_bit_cast(unsigned, tm[12]),      \
                                 0x00000400u);                              \
      yb = __builtin_amdgcn_perm(__builtin_bit_cast(unsigned, tm[15]),      \
                                 __builtin_bit_cast(unsigned, tm[14]),      \
                                 0x00000400u);                              \
      QD = __builtin_amdgcn_perm(yb, ya, 0x05040100u);                      \
    }                                                                       \
    uint2v P1 = __builtin_amdgcn_permlane32_swap(QA, QB, false, false);     \
    uint2v P2 = __builtin_amdgcn_permlane32_swap(QC, QD, false, false);     \
    long b1 = (long)(((unsigned long long)P1[1] << 32) | P1[0]);            \
    long b2 = (long)(((unsigned long long)P2[1] << 32) | P2[0]);            \
    __builtin_amdgcn_s_setprio(1);                                          \
    oacc = MFMA8(VV[0], b1, oacc);                                          \
    lacc = MFMA8(ONES8, b1, lacc);                                          \
    oacc = MFMA8(VV[1], b2, oacc);                                          \
    lacc = MFMA8(ONES8, b2, lacc);                                          \
    __builtin_amdgcn_s_setprio(0);                                          \
  } while (0)

  long2v ak, av, bk, bv;
  LOADT(0, ak, av);
  LOADT(1, bk, bv);
  for (int tt = 0; tt < 128; tt += 2) {
    long2v ck, cv, dk, dv;
    if (tt + 2 < 128) LOADT(tt + 2, ck, cv);
    ABODY(ak, av);
    if (tt + 3 < 128) LOADT(tt + 3, dk, dv);
    ABODY(bk, bv);
    ak = ck; av = cv;
    bk = dk; bv = dv;
  }
#undef LOADT
#undef ABODY

  // normalize and publish O for this head: ls_all[w][q][d] (bf16)
  float inv = 1.0f / lacc[0];
#pragma unroll
  for (int r = 0; r < 16; ++r) {
    int row = (r & 3) + 8 * (r >> 2) + 4 * hi;
    ls_all[w][lo][row] = f2bf(oacc[r] * inv);
  }
  __syncthreads();

  // ---- proj GEMM (bf16): wave w computes out cols [w*32, w*32+32) ----
  f32x16 acc = zero16();
  const bf16x8* bp = (const bf16x8*)(wpf + (w * 16) * 512 + l * 8);
#pragma unroll
  for (int s = 0; s < 16; ++s) {
    bf16x8 afr = *(const bf16x8*)&ls_all[s >> 1][lo][(s & 1) * 16 + 8 * hi];
    acc = MFMA32(afr, bp[s * 64], acc);
  }
  int c0 = w * 32;
  float bias = bpj[c0 + lo];
#pragma unroll
  for (int r = 0; r < 16; ++r) {
    int row = (r & 3) + 8 * (r >> 2) + 4 * hi;
    lsf[w][row][lo] = acc[r] + bias;        // [token][col], per-wave
  }
  // lsf written and read by the same wave: no barrier needed.
  int n0 = qt * 32;
#pragma unroll
  for (int r2 = 0; r2 < 16; ++r2) {
    int cl = 2 * r2 + hi;
    int idx = (((b << 8) + c0 + cl) << 12) + n0 + lo;
    out[idx] = lsf[w][lo][cl] + x[idx];
  }
}

extern "C" void kernel_launch(void* const* d_in, const int* in_sizes, int n_in,
                              void* d_out, int out_size, void* d_ws, size_t ws_size,
                              hipStream_t stream) {
  const float* x      = (const float*)d_in[0];
  const float* gamma  = (const float*)d_in[1];
  const float* beta   = (const float*)d_in[2];
  const float* w_qkv  = (const float*)d_in[3];
  const float* w_proj = (const float*)d_in[4];
  const float* b_proj = (const float*)d_in[5];
  float* out = (float*)d_out;
  char* ws = (char*)d_ws;
  const size_t MB = 1024 * 1024;
  u8*  qgf = (u8*)(ws);             // 2 MB fp8 Q fragments [16][128][1024]
  u8*  kgf = (u8*)(ws + 2 * MB);    // 2 MB fp8 K fragments
  u8*  vgf = (u8*)(ws + 4 * MB);    // 2 MB fp8 V^T fragments
  u16* wqf = (u16*)(ws + 6 * MB);   // 384 KB bf16 W_qkv fragments
  u16* wpf = (u16*)(ws + 6 * MB + 768 * 256 * sizeof(u16)); // 128 KB

  hipLaunchKernelGGL(convw_kernel, dim3(128), dim3(256), 0, stream,
                     w_qkv, w_proj, wqf, wpf);
  hipLaunchKernelGGL(prepqkv_kernel, dim3(256), dim3(256), 0, stream,
                     x, gamma, beta, wqf, qgf, kgf, vgf);
  hipLaunchKernelGGL(attn_proj_kernel, dim3(256), dim3(512), 0, stream,
                     qgf, kgf, vgf, wpf, b_proj, x, out);
}

// Round 13
// 118.864 us; speedup vs baseline: 1.6739x; 1.0772x over previous
//
#include <hip/hip_runtime.h>

typedef __bf16 bf16x8 __attribute__((ext_vector_type(8)));
typedef float f32x16 __attribute__((ext_vector_type(16)));
typedef unsigned int uint4v __attribute__((ext_vector_type(4)));
typedef unsigned int uint2v __attribute__((ext_vector_type(2)));
typedef long long2v __attribute__((ext_vector_type(2)));
typedef unsigned short u16;
typedef unsigned char u8;

#define MFMA32(a, b, c) __builtin_amdgcn_mfma_f32_32x32x16_bf16((a), (b), (c), 0, 0, 0)
#define MFMA8(a, b, c) __builtin_amdgcn_mfma_f32_32x32x16_fp8_fp8((a), (b), (c), 0, 0, 0)

static __device__ __forceinline__ u16 f2bf(float f) {
  unsigned u = __builtin_bit_cast(unsigned, f);
  u += 0x7fffu + ((u >> 16) & 1u);
  return (u16)(u >> 16);
}

static __device__ __forceinline__ f32x16 zero16() {
  f32x16 z;
#pragma unroll
  for (int i = 0; i < 16; ++i) z[i] = 0.0f;
  return z;
}

// bf16 fragment-major (for GEMM operands): frag_s[lane][i] =
//   T[lane&31][s*16 + 8*(lane>>5) + i], buf[(tile*16+s)*512 + lane*8 + i].
// fp8 fragment-major (for attn operands), 1 KB per 32x32 tile:
//   lane l holds 16 bytes: j=0..7  -> T[l&31][(l>>5)*8 + j]
//                          j=8..15 -> T[l&31][16 + (l>>5)*8 + j]

// ---------------- weights fp32 -> bf16 fragment-major ----------------
__global__ __launch_bounds__(256) void convw_kernel(
    const float* __restrict__ wq, const float* __restrict__ wp,
    u16* __restrict__ wqf, u16* __restrict__ wpf) {
  int t = threadIdx.x;
  int u = (blockIdx.x << 2) + (t >> 6);
  int l = t & 63, lo = l & 31, hi = l >> 5;
  const float* src; u16* dst; int ot, s;
  if (u < 384) { ot = u >> 4; s = u & 15; src = wq; dst = wqf; }
  else { int u2 = u - 384; ot = u2 >> 4; s = u2 & 15; src = wp; dst = wpf; }
  const float* p = src + (ot * 32 + lo) * 256 + s * 16 + 8 * hi;
  bf16x8 f;
#pragma unroll
  for (int i = 0; i < 8; ++i) f[i] = (__bf16)p[i];
  *(bf16x8*)(dst + (ot * 16 + s) * 512 + l * 8) = f;
}

// ---------- fused LayerNorm + QKV GEMM, fp8 fragment outputs ----------
// 512 threads / 8 waves (2 waves/SIMD for latency hiding). Wave w does
// 2 A-fragment slices in LN and 3 o-tiles in the GEMM phase.
__global__ __launch_bounds__(512) void prepqkv_kernel(
    const float* __restrict__ x, const float* __restrict__ gamma,
    const float* __restrict__ beta, const u16* __restrict__ wqf,
    u8* __restrict__ qgf, u8* __restrict__ kgf, u8* __restrict__ vgf) {
  __shared__ float xs[32][257];
  __shared__ float red[2][16][32];
  __shared__ float mu_s[32], rs_s[32];
  __shared__ float gs[256], bs[256];
  __shared__ u16 af[16 * 512];        // A fragments (bf16), 16 KB
  __shared__ u8 ls8[8][32][32];       // per-wave fp8 transpose bounce, 8 KB
  int t = threadIdx.x;
  int mt = blockIdx.x;
  int n0g = mt * 32;
  int bb = n0g >> 12, nn = n0g & 4095;
  int ni = t & 31, g = t >> 5;        // g in 0..15
  if (t < 256) { gs[t] = gamma[t]; bs[t] = beta[t]; }
  float s1 = 0.f, s2 = 0.f;
  for (int c = g; c < 256; c += 16) {
    float v = x[(((bb << 8) + c) << 12) + nn + ni];
    xs[ni][c] = v;
    s1 += v; s2 += v * v;
  }
  red[0][g][ni] = s1; red[1][g][ni] = s2;
  __syncthreads();
  if (t < 32) {
    float ss = 0.f, qq = 0.f;
#pragma unroll
    for (int k = 0; k < 16; ++k) { ss += red[0][k][t]; qq += red[1][k][t]; }
    float mean = ss * (1.f / 256.f);
    float var = qq * (1.f / 256.f) - mean * mean;
    mu_s[t] = mean;
    rs_s[t] = rsqrtf(var + 1e-5f);
  }
  __syncthreads();
  int l = t & 63, w = t >> 6, lo = l & 31, hi = l >> 5;
  {
    float mu = mu_s[lo], rs = rs_s[lo];
#pragma unroll
    for (int jj = 0; jj < 2; ++jj) {
      int s = w * 2 + jj;
      bf16x8 f;
#pragma unroll
      for (int i = 0; i < 8; ++i) {
        int c = s * 16 + 8 * hi + i;
        f[i] = (__bf16)((xs[lo][c] - mu) * rs * gs[c] + bs[c]);
      }
      *(bf16x8*)(af + s * 512 + l * 8) = f;
    }
  }
  __syncthreads();

  // ---- phase 2: A-tile in registers, 3 o-tiles per wave, fp8 epilogue ----
  bf16x8 ar[16];
#pragma unroll
  for (int s = 0; s < 16; ++s) ar[s] = *(const bf16x8*)(af + s * 512 + l * 8);
  int n0 = n0g & 4095;
  int tt = n0 >> 5;                 // token tile within batch
#pragma unroll
  for (int oi = 0; oi < 3; ++oi) {
    int ot = w * 3 + oi;
    int o0 = ot * 32;
    f32x16 acc = zero16();
    const bf16x8* bp = (const bf16x8*)(wqf + (ot * 16) * 512 + l * 8);
#pragma unroll
    for (int s = 0; s < 16; ++s) acc = MFMA32(ar[s], bp[s * 64], acc);
    int sec = o0 >> 8;              // 0=q 1=k 2=v
    int hh = (o0 & 255) >> 5;       // head; d = lo
    // convert to fp8 e4m3 and transpose-bounce through LDS.
    // acc[r]: token = (r&3)+8*(r>>2)+4*hi (pairs r,r+1 are adjacent tokens)
    if (sec == 2) {
      // V^T layout: ls8[d][token]; adjacent tokens -> u16 store
#pragma unroll
      for (int j = 0; j < 8; ++j) {
        int rr = 2 * j;
        int row = (rr & 3) + 8 * (rr >> 2) + 4 * hi;
        int pk2 = __builtin_amdgcn_cvt_pk_fp8_f32(acc[rr], acc[rr + 1], 0, false);
        *(u16*)&ls8[w][lo][row] = (u16)pk2;
      }
    } else {
      // Q/K layout: ls8[token][d]
#pragma unroll
      for (int j = 0; j < 8; ++j) {
        int rr = 2 * j;
        int row = (rr & 3) + 8 * (rr >> 2) + 4 * hi;
        int pk2 = __builtin_amdgcn_cvt_pk_fp8_f32(acc[rr], acc[rr + 1], 0, false);
        ls8[w][row][lo] = (u8)pk2;
        ls8[w][row + 1][lo] = (u8)(pk2 >> 8);
      }
    }
    // fragment read: row lo, bytes [hi*8,+8) and [16+hi*8,+8)
    unsigned long long w0 = *(const unsigned long long*)&ls8[w][lo][hi * 8];
    unsigned long long w1 = *(const unsigned long long*)&ls8[w][lo][16 + hi * 8];
    int bh = (bb << 3) + hh;
    u8* base = (sec == 0) ? qgf : ((sec == 1) ? kgf : vgf);
    u8* dst = base + (((size_t)bh * 128 + tt) << 10) + l * 16;
    ((unsigned long long*)dst)[0] = w0;
    ((unsigned long long*)dst)[1] = w1;
  }
}

// ---------- Fused attention (fp8) + proj + residual + token2patch ----------
// Block decode is XCD-aware: b = (bid>>2)&1, qt = (bid&3)|((bid>>3)<<2) so
// (assuming bid%8 XCD round-robin) XCDs 0-3 serve batch 0, 4-7 batch 1 --
// halves each XCD's K/V working set to 2 MB (fits 4 MB L2).
// 4-deep tile prefetch (6 buffers) to cover L2 latency at 2 waves/SIMD.
__global__ __launch_bounds__(512) void attn_proj_kernel(
    const u8* __restrict__ qgf, const u8* __restrict__ kgf,
    const u8* __restrict__ vgf, const u16* __restrict__ wpf,
    const float* __restrict__ bpj, const float* __restrict__ x,
    float* __restrict__ out) {
  __shared__ u16 ls_all[8][32][32];   // O[head][q][d] bf16, normalized
  __shared__ float lsf[8][32][33];    // proj epilogue bounce, per wave
  int t = threadIdx.x;
  int l = t & 63, w = t >> 6, lo = l & 31, hi = l >> 5;
  int bid = blockIdx.x;
  int b = (bid >> 2) & 1;
  int qt = (bid & 3) | ((bid >> 3) << 2);
  int bh = (b << 3) + w;              // wave w owns head w
  long2v qf = *(const long2v*)(qgf + (((size_t)bh * 128 + qt) << 10) + l * 16);
  const u8* kfb = kgf + (size_t)bh * 131072 + l * 16;
  const u8* vfb = vgf + (size_t)bh * 131072 + l * 16;
  const f32x16 zf = zero16();
  f32x16 oacc = zero16();
  f32x16 lacc = zero16();
  const long ONES8 = 0x3838383838383838L;  // e4m3 1.0 x8
  const float C1 = 8.0f * 0.17677669529663688f * 1.4426950408889634f;
  const float C2 = 8388664.0f;             // 2^23 + 56 (e4m3 exp bias<<3)

#define LOADT(T, KK, VV) do {                          \
    KK = *(const long2v*)(kfb + (T) * 1024);           \
    VV = *(const long2v*)(vfb + (T) * 1024);           \
  } while (0)

#define ABODY(KK, VV) do {                                                  \
    f32x16 sa = MFMA8(KK[0], qf[0], zf);                                    \
    sa = MFMA8(KK[1], qf[1], sa);                                           \
    f32x16 tm = sa * C1 + C2;                                               \
    unsigned QA, QB, QC, QD;                                                \
    {                                                                       \
      unsigned ya, yb;                                                      \
      ya = __builtin_amdgcn_perm(__builtin_bit_cast(unsigned, tm[1]),       \
                                 __builtin_bit_cast(unsigned, tm[0]),       \
                                 0x00000400u);                              \
      yb = __builtin_amdgcn_perm(__builtin_bit_cast(unsigned, tm[3]),       \
                                 __builtin_bit_cast(unsigned, tm[2]),       \
                                 0x00000400u);                              \
      QA = __builtin_amdgcn_perm(yb, ya, 0x05040100u);                      \
      ya = __builtin_amdgcn_perm(__builtin_bit_cast(unsigned, tm[5]),       \
                                 __builtin_bit_cast(unsigned, tm[4]),       \
                                 0x00000400u);                              \
      yb = __builtin_amdgcn_perm(__builtin_bit_cast(unsigned, tm[7]),       \
                                 __builtin_bit_cast(unsigned, tm[6]),       \
                                 0x00000400u);                              \
      QB = __builtin_amdgcn_perm(yb, ya, 0x05040100u);                      \
      ya = __builtin_amdgcn_perm(__builtin_bit_cast(unsigned, tm[9]),       \
                                 __builtin_bit_cast(unsigned, tm[8]),       \
                                 0x00000400u);                              \
      yb = __builtin_amdgcn_perm(__builtin_bit_cast(unsigned, tm[11]),      \
                                 __builtin_bit_cast(unsigned, tm[10]),      \
                                 0x00000400u);                              \
      QC = __builtin_amdgcn_perm(yb, ya, 0x05040100u);                      \
      ya = __builtin_amdgcn_perm(__builtin_bit_cast(unsigned, tm[13]),      \
                                 __builtin_bit_cast(unsigned, tm[12]),      \
                                 0x00000400u);                              \
      yb = __builtin_amdgcn_perm(__builtin_bit_cast(unsigned, tm[15]),      \
                                 __builtin_bit_cast(unsigned, tm[14]),      \
                                 0x00000400u);                              \
      QD = __builtin_amdgcn_perm(yb, ya, 0x05040100u);                      \
    }                                                                       \
    uint2v P1 = __builtin_amdgcn_permlane32_swap(QA, QB, false, false);     \
    uint2v P2 = __builtin_amdgcn_permlane32_swap(QC, QD, false, false);     \
    long b1 = (long)(((unsigned long long)P1[1] << 32) | P1[0]);            \
    long b2 = (long)(((unsigned long long)P2[1] << 32) | P2[0]);            \
    __builtin_amdgcn_s_setprio(1);                                          \
    oacc = MFMA8(VV[0], b1, oacc);                                          \
    lacc = MFMA8(ONES8, b1, lacc);                                          \
    oacc = MFMA8(VV[1], b2, oacc);                                          \
    lacc = MFMA8(ONES8, b2, lacc);                                          \
    __builtin_amdgcn_s_setprio(0);                                          \
  } while (0)

  long2v k0, v0, k1, v1, k2, v2, k3, v3, k4, v4, k5, v5;
  LOADT(0, k0, v0);
  LOADT(1, k1, v1);
  LOADT(2, k2, v2);
  LOADT(3, k3, v3);
  for (int tt = 0; tt < 128; tt += 2) {
    if (tt + 4 < 128) LOADT(tt + 4, k4, v4);
    ABODY(k0, v0);
    if (tt + 5 < 128) LOADT(tt + 5, k5, v5);
    ABODY(k1, v1);
    k0 = k2; v0 = v2; k1 = k3; v1 = v3;
    k2 = k4; v2 = v4; k3 = k5; v3 = v5;
  }
#undef LOADT
#undef ABODY

  // normalize and publish O for this head: ls_all[w][q][d] (bf16)
  float inv = 1.0f / lacc[0];
#pragma unroll
  for (int r = 0; r < 16; ++r) {
    int row = (r & 3) + 8 * (r >> 2) + 4 * hi;
    ls_all[w][lo][row] = f2bf(oacc[r] * inv);
  }
  __syncthreads();

  // ---- proj GEMM (bf16): wave w computes out cols [w*32, w*32+32) ----
  f32x16 acc = zero16();
  const bf16x8* bp = (const bf16x8*)(wpf + (w * 16) * 512 + l * 8);
#pragma unroll
  for (int s = 0; s < 16; ++s) {
    bf16x8 afr = *(const bf16x8*)&ls_all[s >> 1][lo][(s & 1) * 16 + 8 * hi];
    acc = MFMA32(afr, bp[s * 64], acc);
  }
  int c0 = w * 32;
  float bias = bpj[c0 + lo];
#pragma unroll
  for (int r = 0; r < 16; ++r) {
    int row = (r & 3) + 8 * (r >> 2) + 4 * hi;
    lsf[w][row][lo] = acc[r] + bias;        // [token][col], per-wave
  }
  // lsf written and read by the same wave: no barrier needed.
  int n0 = qt * 32;
#pragma unroll
  for (int r2 = 0; r2 < 16; ++r2) {
    int cl = 2 * r2 + hi;
    int idx = (((b << 8) + c0 + cl) << 12) + n0 + lo;
    out[idx] = lsf[w][lo][cl] + x[idx];
  }
}

extern "C" void kernel_launch(void* const* d_in, const int* in_sizes, int n_in,
                              void* d_out, int out_size, void* d_ws, size_t ws_size,
                              hipStream_t stream) {
  const float* x      = (const float*)d_in[0];
  const float* gamma  = (const float*)d_in[1];
  const float* beta   = (const float*)d_in[2];
  const float* w_qkv  = (const float*)d_in[3];
  const float* w_proj = (const float*)d_in[4];
  const float* b_proj = (const float*)d_in[5];
  float* out = (float*)d_out;
  char* ws = (char*)d_ws;
  const size_t MB = 1024 * 1024;
  u8*  qgf = (u8*)(ws);             // 2 MB fp8 Q fragments [16][128][1024]
  u8*  kgf = (u8*)(ws + 2 * MB);    // 2 MB fp8 K fragments
  u8*  vgf = (u8*)(ws + 4 * MB);    // 2 MB fp8 V^T fragments
  u16* wqf = (u16*)(ws + 6 * MB);   // 384 KB bf16 W_qkv fragments
  u16* wpf = (u16*)(ws + 6 * MB + 768 * 256 * sizeof(u16)); // 128 KB

  hipLaunchKernelGGL(convw_kernel, dim3(128), dim3(256), 0, stream,
                     w_qkv, w_proj, wqf, wpf);
  hipLaunchKernelGGL(prepqkv_kernel, dim3(256), dim3(512), 0, stream,
                     x, gamma, beta, wqf, qgf, kgf, vgf);
  hipLaunchKernelGGL(attn_proj_kernel, dim3(256), dim3(512), 0, stream,
                     qgf, kgf, vgf, wpf, b_proj, x, out);
}